// Round 5
// baseline (1673.878 us; speedup 1.0000x reference)
//
#include <hip/hip_runtime.h>
#include <hip/hip_fp16.h>
#include <math.h>

#define N_NODES 100000
#define N_EDGES 1600000
#define IN_DIM 128
#define F_DIM 128      // HEADS*OUT_DIM
#define NEG_SLOPE 0.2f

#define BUCKW_LOG 7            // 128 nodes per bucket
#define NBUCK 784              // covers 100352 >= N_NODES
#define NBLK 128               // hist/bscat blocks
#define EPB 12500              // edges per block (NBLK*EPB == N_EDGES); int4-aligned
#define GB 1563                // gemm blocks: ceil(100000/64); bscat rides after
#define CURSTRIDE 16           // pad bucket cursors to one 64B line each

typedef short v8s __attribute__((ext_vector_type(8)));
typedef float v4f __attribute__((ext_vector_type(4)));

static __device__ __forceinline__ unsigned short f2bf(float f) {
    unsigned u = __float_as_uint(f);
    u += 0x7fffu + ((u >> 16) & 1u);
    return (unsigned short)(u >> 16);
}
static __device__ __forceinline__ float lo2f(unsigned u) { return __uint_as_float(u << 16); }
static __device__ __forceinline__ float hi2f(unsigned u) { return __uint_as_float(u & 0xffff0000u); }

// ---------------- hist: per-bucket edge counts (+ fused W transpose/convert) --
__global__ __launch_bounds__(1024) void k_hist(const int* __restrict__ ei_dst,
                                               int* __restrict__ pcur,
                                               const float* __restrict__ W,
                                               unsigned short* __restrict__ Wt) {
    if (blockIdx.x < 16) {               // wprep: 16 blocks x 1024 = 16384 elems
        int i = blockIdx.x * 1024 + threadIdx.x;
        int n = i >> 7, k = i & 127;
        Wt[n * 128 + k] = f2bf(W[k * 128 + n]);
    }
    __shared__ int hist[NBUCK];
    for (int i = threadIdx.x; i < NBUCK; i += 1024) hist[i] = 0;
    __syncthreads();
    const int4* p = (const int4*)(ei_dst + blockIdx.x * EPB);
    for (int i = threadIdx.x; i < EPB / 4; i += 1024) {
        int4 d = p[i];
        atomicAdd(&hist[d.x >> BUCKW_LOG], 1);
        atomicAdd(&hist[d.y >> BUCKW_LOG], 1);
        atomicAdd(&hist[d.z >> BUCKW_LOG], 1);
        atomicAdd(&hist[d.w >> BUCKW_LOG], 1);
    }
    __syncthreads();
    for (int b = threadIdx.x; b < NBUCK; b += 1024) {
        int h = hist[b];
        if (h) atomicAdd(&pcur[b * CURSTRIDE], h);
    }
}

// ---------------- single-launch 784-entry exclusive scan ---------------------
__global__ __launch_bounds__(1024) void k_scan(int* __restrict__ pcur,
                                               int* __restrict__ boff) {
    __shared__ int sh[1024];
    int t = threadIdx.x;
    int v = (t < NBUCK) ? pcur[t * CURSTRIDE] : 0;
    sh[t] = v;
    __syncthreads();
    for (int off = 1; off < 1024; off <<= 1) {
        int y = (t >= off) ? sh[t - off] : 0;
        __syncthreads();
        sh[t] += y;
        __syncthreads();
    }
    int ex = sh[t] - v;                  // exclusive
    if (t < NBUCK) { boff[t] = ex; pcur[t * CURSTRIDE] = ex; }
    if (t == NBUCK - 1) boff[NBUCK] = ex + v;   // == N_EDGES
}

// ---------------- MEGA: GEMM tiles (blocks < GB) + bscat (blocks >= GB) ------
// GEMM: h16 = bf16(x @ W) via MFMA, fused a_src/a_dst epilogue (proven).
// bscat: scatter edges into bucket-grouped ebuf via 64B-padded global cursors
// (bucket windows ~8KB -> L2-local writes; order within bucket irrelevant).
__global__ __launch_bounds__(256) void k_mega(const float* __restrict__ x,
                                              const unsigned short* __restrict__ Wt,
                                              unsigned short* __restrict__ h16,
                                              const float* __restrict__ att_src,
                                              const float* __restrict__ att_dst,
                                              float* __restrict__ a_src,
                                              float* __restrict__ a_dst,
                                              const int* __restrict__ ei,
                                              int* __restrict__ pcur,
                                              int* __restrict__ ebuf) {
    if (blockIdx.x >= GB) {               // ---- bscat part ----
        int blk = blockIdx.x - GB;
        const int4* ps = (const int4*)(ei + blk * EPB);
        const int4* pd = (const int4*)(ei + N_EDGES + blk * EPB);
        for (int i = threadIdx.x; i < EPB / 4; i += 256) {
            int4 s = ps[i];
            int4 d = pd[i];
            int p0 = atomicAdd(&pcur[(d.x >> BUCKW_LOG) * CURSTRIDE], 1);
            ebuf[p0] = s.x | ((d.x & 127) << 17);
            int p1 = atomicAdd(&pcur[(d.y >> BUCKW_LOG) * CURSTRIDE], 1);
            ebuf[p1] = s.y | ((d.y & 127) << 17);
            int p2 = atomicAdd(&pcur[(d.z >> BUCKW_LOG) * CURSTRIDE], 1);
            ebuf[p2] = s.z | ((d.z & 127) << 17);
            int p3 = atomicAdd(&pcur[(d.w >> BUCKW_LOG) * CURSTRIDE], 1);
            ebuf[p3] = s.w | ((d.w & 127) << 17);
        }
        return;
    }

    __shared__ unsigned short As[64][136];    // [row][k]
    __shared__ unsigned short Bs[128][136];   // [n][k]
    __shared__ float attl[256];               // [0..127]=att_src, [128..255]=att_dst
    const int t  = threadIdx.x;
    const int n0 = blockIdx.x * 64;

    attl[t] = (t < 128) ? att_src[t] : att_dst[t - 128];

    {
        int row = t >> 2, k0 = (t & 3) * 32;
        int n = n0 + row;
        #pragma unroll
        for (int i = 0; i < 4; i++) {
            float4 va = make_float4(0.f,0.f,0.f,0.f), vb = va;
            if (n < N_NODES) {
                const float* p = x + (size_t)n * IN_DIM + k0 + i * 8;
                va = *(const float4*)p;
                vb = *(const float4*)(p + 4);
            }
            uint4 u;
            u.x = f2bf(va.x) | ((unsigned)f2bf(va.y) << 16);
            u.y = f2bf(va.z) | ((unsigned)f2bf(va.w) << 16);
            u.z = f2bf(vb.x) | ((unsigned)f2bf(vb.y) << 16);
            u.w = f2bf(vb.z) | ((unsigned)f2bf(vb.w) << 16);
            *(uint4*)&As[row][k0 + i * 8] = u;
        }
    }
    {
        int nr = t >> 1, s0 = (t & 1) * 64;
        const uint4* src = (const uint4*)(Wt + nr * 128 + s0);
        #pragma unroll
        for (int i = 0; i < 8; i++)
            *(uint4*)&Bs[nr][s0 + i * 8] = src[i];
    }
    __syncthreads();

    const int w = t >> 6, lane = t & 63;
    const int mr = lane & 15, quad = lane >> 4;
    const int m0 = w * 16;

    v4f acc[8];
    #pragma unroll
    for (int nt = 0; nt < 8; nt++) acc[nt] = (v4f){0.f, 0.f, 0.f, 0.f};

    #pragma unroll
    for (int kk = 0; kk < 4; kk++) {
        int kof = kk * 32 + quad * 8;
        v8s a = *(const v8s*)&As[m0 + mr][kof];
        #pragma unroll
        for (int nt = 0; nt < 8; nt++) {
            v8s b = *(const v8s*)&Bs[nt * 16 + mr][kof];
            acc[nt] = __builtin_amdgcn_mfma_f32_16x16x32_bf16(a, b, acc[nt], 0, 0, 0);
        }
    }

    #pragma unroll
    for (int nt = 0; nt < 8; nt++)
        #pragma unroll
        for (int r = 0; r < 4; r++)
            As[m0 + quad * 4 + r][nt * 16 + mr] = f2bf(acc[nt][r]);
    __syncthreads();
    {
        int row = m0 + (lane >> 2);
        int c0  = (lane & 3) * 32;        // 32 cols = one head
        int n = n0 + row;
        if (n < N_NODES) {
            float ds = 0.f, dd = 0.f;
            #pragma unroll
            for (int i = 0; i < 4; i++) {
                uint4 v = *(const uint4*)&As[row][c0 + i * 8];
                *(uint4*)&h16[(size_t)n * F_DIM + c0 + i * 8] = v;
                float f0 = lo2f(v.x), f1 = hi2f(v.x);
                float f2 = lo2f(v.y), f3 = hi2f(v.y);
                float f4 = lo2f(v.z), f5 = hi2f(v.z);
                float f6 = lo2f(v.w), f7 = hi2f(v.w);
                const float* ps = &attl[c0 + i * 8];
                const float* pd = &attl[128 + c0 + i * 8];
                ds += f0*ps[0] + f1*ps[1] + f2*ps[2] + f3*ps[3]
                    + f4*ps[4] + f5*ps[5] + f6*ps[6] + f7*ps[7];
                dd += f0*pd[0] + f1*pd[1] + f2*pd[2] + f3*pd[3]
                    + f4*pd[4] + f5*pd[5] + f6*pd[6] + f7*pd[7];
            }
            int hd = lane & 3;
            a_src[n * 4 + hd] = ds;
            a_dst[n * 4 + hd] = dd;
        }
    }
}

// ---------------- agg2: one block per bucket, LDS accumulators ---------------
// Consumes the bucket's UNSORTED ebuf segment directly (no csr2/ebounds/pads).
// Each wave takes 1 edge/step: 64-lane coalesced 256B h16 gather, inline
// q = exp(leakyrelu(a_src[s]+a_dst[d])), ds_add_f32 into acc[128][128].
__global__ __launch_bounds__(1024) void k_agg2(const unsigned short* __restrict__ h16,
                                               const float* __restrict__ a_src,
                                               const float* __restrict__ a_dst,
                                               const int* __restrict__ boff,
                                               const int* __restrict__ ebuf,
                                               const float* __restrict__ bias,
                                               float* __restrict__ out) {
    __shared__ float acc[128][128];    // 64KB -> 2 blocks/CU, 32 waves/CU
    __shared__ float den[128][4];
    __shared__ float adl[128][4];
    int b = blockIdx.x, t = threadIdx.x;
    int node0 = b << BUCKW_LOG;

    if (t < 512) {                     // a_dst local + self-loop seed of denom
        int r = t >> 2, h = t & 3;
        int n = node0 + r;
        bool ok = n < N_NODES;
        float ad = ok ? a_dst[n * 4 + h] : 0.f;
        float as = ok ? a_src[n * 4 + h] : 0.f;
        adl[r][h] = ad;
        float e = as + ad; e = e > 0.f ? e : NEG_SLOPE * e;
        den[r][h] = __expf(e);
    }
    __syncthreads();
    // acc init with self-loop contribution: acc[r][c] = p0[r][c/32]*h16[n][c]
    for (int i = t; i < 128 * 64; i += 1024) {
        int r = i >> 6, c2 = (i & 63) * 2;
        int n = node0 + r;
        unsigned hv = (n < N_NODES) ? *(const unsigned*)(h16 + (size_t)n * 128 + c2) : 0u;
        float p = den[r][c2 >> 5];
        acc[r][c2]     = p * lo2f(hv);
        acc[r][c2 + 1] = p * hi2f(hv);
    }
    __syncthreads();

    int beg = boff[b], end = boff[b + 1];
    int wv = t >> 6, lane = t & 63;
    int h = lane >> 4;                 // head of feats {2*lane, 2*lane+1}
    int c2 = lane * 2;
    int j = beg + wv;
    for (; j + 16 < end; j += 32) {    // unroll 2 (independent edges)
        int u0 = ebuf[j];
        int u1 = ebuf[j + 16];
        int s0 = u0 & 0x1ffff, d0 = (u0 >> 17) & 127;
        int s1 = u1 & 0x1ffff, d1 = (u1 >> 17) & 127;
        unsigned hv0 = *(const unsigned*)(h16 + (size_t)s0 * 128 + c2);
        unsigned hv1 = *(const unsigned*)(h16 + (size_t)s1 * 128 + c2);
        float as0 = a_src[s0 * 4 + h];
        float as1 = a_src[s1 * 4 + h];
        float e0 = as0 + adl[d0][h]; e0 = e0 > 0.f ? e0 : NEG_SLOPE * e0;
        float e1 = as1 + adl[d1][h]; e1 = e1 > 0.f ? e1 : NEG_SLOPE * e1;
        float q0 = __expf(e0);
        float q1 = __expf(e1);
        atomicAdd(&acc[d0][c2],     q0 * lo2f(hv0));
        atomicAdd(&acc[d0][c2 + 1], q0 * hi2f(hv0));
        atomicAdd(&acc[d1][c2],     q1 * lo2f(hv1));
        atomicAdd(&acc[d1][c2 + 1], q1 * hi2f(hv1));
        if ((lane & 15) == 0) {
            atomicAdd(&den[d0][h], q0);
            atomicAdd(&den[d1][h], q1);
        }
    }
    if (j < end) {
        int u0 = ebuf[j];
        int s0 = u0 & 0x1ffff, d0 = (u0 >> 17) & 127;
        unsigned hv0 = *(const unsigned*)(h16 + (size_t)s0 * 128 + c2);
        float as0 = a_src[s0 * 4 + h];
        float e0 = as0 + adl[d0][h]; e0 = e0 > 0.f ? e0 : NEG_SLOPE * e0;
        float q0 = __expf(e0);
        atomicAdd(&acc[d0][c2],     q0 * lo2f(hv0));
        atomicAdd(&acc[d0][c2 + 1], q0 * hi2f(hv0));
        if ((lane & 15) == 0) atomicAdd(&den[d0][h], q0);
    }
    __syncthreads();
    // finalize: normalize + bias + ELU, fully-coalesced f32 stream out
    for (int i = t; i < 128 * 128; i += 1024) {
        int r = i >> 7, c = i & 127;
        int n = node0 + r;
        if (n < N_NODES) {
            float inv = 1.f / (den[r][c >> 5] + 1e-16f);
            float o = acc[r][c] * inv + bias[c];
            o = o > 0.f ? o : __expf(o) - 1.f;
            out[(size_t)n * F_DIM + c] = o;
        }
    }
}

extern "C" void kernel_launch(void* const* d_in, const int* in_sizes, int n_in,
                              void* d_out, int out_size, void* d_ws, size_t ws_size,
                              hipStream_t stream) {
    const float* x       = (const float*)d_in[0];
    const int*   ei      = (const int*)d_in[1];   // (2, E) row-major int32
    const float* W       = (const float*)d_in[2];
    const float* att_src = (const float*)d_in[3];
    const float* att_dst = (const float*)d_in[4];
    const float* bias    = (const float*)d_in[5];
    float*       out     = (float*)d_out;

    char* ws = (char*)d_ws;
    unsigned short* h16 = (unsigned short*)ws; ws += (size_t)N_NODES * F_DIM * 2;   // 25.6 MB
    unsigned short* Wt  = (unsigned short*)ws; ws += (size_t)IN_DIM * F_DIM * 2;    // 32 KB
    float* a_src  = (float*)ws; ws += (size_t)N_NODES * 4 * 4;                      // 1.6 MB
    float* a_dst  = (float*)ws; ws += (size_t)N_NODES * 4 * 4;                      // 1.6 MB
    int*   pcur   = (int*)ws;   ws += (size_t)NBUCK * CURSTRIDE * 4;                // 50 KB
    int*   boff   = (int*)ws;   ws += 4096;
    int*   ebuf   = (int*)ws;   ws += (size_t)N_EDGES * 4;                          // 6.4 MB

    hipMemsetAsync(pcur, 0, (size_t)NBUCK * CURSTRIDE * 4, stream);
    k_hist<<<NBLK, 1024, 0, stream>>>(ei + N_EDGES, pcur, W, Wt);
    k_scan<<<1, 1024, 0, stream>>>(pcur, boff);
    k_mega<<<GB + NBLK, 256, 0, stream>>>(x, Wt, h16, att_src, att_dst,
                                          a_src, a_dst, ei, pcur, ebuf);
    k_agg2<<<NBUCK, 1024, 0, stream>>>(h16, a_src, a_dst, boff, ebuf, bias, out);
}

// Round 6
// 336.759 us; speedup vs baseline: 4.9706x; 4.9706x over previous
//
#include <hip/hip_runtime.h>
#include <hip/hip_fp16.h>
#include <math.h>

#define N_NODES 100000
#define N_EDGES 1600000
#define IN_DIM 128
#define F_DIM 128      // HEADS*OUT_DIM
#define NEG_SLOPE 0.2f

#define BUCKW_LOG 7            // 128 nodes per bucket
#define NBUCK 784              // covers 100352 >= N_NODES
#define BUCK_CAP 3072          // static ebuf slots/bucket (mean 2048, +22 sigma)
#define CSR_STRIDE 3584        // csr2 slots/bucket (3072 edges + 128*3 pads + slack)
#define CURSTRIDE 16           // pad bucket cursors to one 64B line each
#define GB 1563                // gemm blocks: ceil(100000/64)
#define SBB 400                // bscat blocks fused after gemm blocks
#define EPSB 4000              // edges per bscat block (SBB*EPSB == N_EDGES, int4-aligned)
#define PADBIT 0x80000000u

typedef short v8s __attribute__((ext_vector_type(8)));
typedef float v4f __attribute__((ext_vector_type(4)));

static __device__ __forceinline__ unsigned short f2bf(float f) {
    unsigned u = __float_as_uint(f);
    u += 0x7fffu + ((u >> 16) & 1u);
    return (unsigned short)(u >> 16);
}
static __device__ __forceinline__ float lo2f(unsigned u) { return __uint_as_float(u << 16); }
static __device__ __forceinline__ float hi2f(unsigned u) { return __uint_as_float(u & 0xffff0000u); }

// ---------------- init: W transpose/convert (blocks 0..15) + cursor zero -----
__global__ __launch_bounds__(1024) void k_init(const float* __restrict__ W,
                                               unsigned short* __restrict__ Wt,
                                               int* __restrict__ pcur) {
    if (blockIdx.x < 16) {
        int i = blockIdx.x * 1024 + threadIdx.x;   // 16384 elems
        int n = i >> 7, k = i & 127;
        Wt[n * 128 + k] = f2bf(W[k * 128 + n]);
    } else {
        for (int i = threadIdx.x; i < NBUCK * CURSTRIDE; i += 1024)
            pcur[i] = 0;
    }
}

// ---------------- MEGA: GEMM tiles (blocks < GB) + bscat (blocks >= GB) ------
// GEMM: h16 = bf16(x @ W) via MFMA, fused a_src/a_dst epilogue (proven).
// bscat: scatter edges into STATIC bucket regions (b*BUCK_CAP) via 64B-padded
// global cursors. 400x256 blocks restores R3's bscat parallelism (R4's
// regression was its 4x-reduced thread count).
__global__ __launch_bounds__(256) void k_mega(const float* __restrict__ x,
                                              const unsigned short* __restrict__ Wt,
                                              unsigned short* __restrict__ h16,
                                              const float* __restrict__ att_src,
                                              const float* __restrict__ att_dst,
                                              float* __restrict__ a_src,
                                              float* __restrict__ a_dst,
                                              const int* __restrict__ ei,
                                              int* __restrict__ pcur,
                                              int* __restrict__ ebuf) {
    if (blockIdx.x >= GB) {               // ---- bscat part ----
        int blk = blockIdx.x - GB;
        const int4* ps = (const int4*)(ei + blk * EPSB);
        const int4* pd = (const int4*)(ei + N_EDGES + blk * EPSB);
        for (int i = threadIdx.x; i < EPSB / 4; i += 256) {
            int4 s = ps[i];
            int4 d = pd[i];
            int b0 = d.x >> BUCKW_LOG;
            int p0 = b0 * BUCK_CAP + atomicAdd(&pcur[b0 * CURSTRIDE], 1);
            ebuf[p0] = s.x | ((d.x & 127) << 17);
            int b1 = d.y >> BUCKW_LOG;
            int p1 = b1 * BUCK_CAP + atomicAdd(&pcur[b1 * CURSTRIDE], 1);
            ebuf[p1] = s.y | ((d.y & 127) << 17);
            int b2 = d.z >> BUCKW_LOG;
            int p2 = b2 * BUCK_CAP + atomicAdd(&pcur[b2 * CURSTRIDE], 1);
            ebuf[p2] = s.z | ((d.z & 127) << 17);
            int b3 = d.w >> BUCKW_LOG;
            int p3 = b3 * BUCK_CAP + atomicAdd(&pcur[b3 * CURSTRIDE], 1);
            ebuf[p3] = s.w | ((d.w & 127) << 17);
        }
        return;
    }

    __shared__ unsigned short As[64][136];    // [row][k]
    __shared__ unsigned short Bs[128][136];   // [n][k]
    __shared__ float attl[256];               // [0..127]=att_src, [128..255]=att_dst
    const int t  = threadIdx.x;
    const int n0 = blockIdx.x * 64;

    attl[t] = (t < 128) ? att_src[t] : att_dst[t - 128];

    {
        int row = t >> 2, k0 = (t & 3) * 32;
        int n = n0 + row;
        #pragma unroll
        for (int i = 0; i < 4; i++) {
            float4 va = make_float4(0.f,0.f,0.f,0.f), vb = va;
            if (n < N_NODES) {
                const float* p = x + (size_t)n * IN_DIM + k0 + i * 8;
                va = *(const float4*)p;
                vb = *(const float4*)(p + 4);
            }
            uint4 u;
            u.x = f2bf(va.x) | ((unsigned)f2bf(va.y) << 16);
            u.y = f2bf(va.z) | ((unsigned)f2bf(va.w) << 16);
            u.z = f2bf(vb.x) | ((unsigned)f2bf(vb.y) << 16);
            u.w = f2bf(vb.z) | ((unsigned)f2bf(vb.w) << 16);
            *(uint4*)&As[row][k0 + i * 8] = u;
        }
    }
    {
        int nr = t >> 1, s0 = (t & 1) * 64;
        const uint4* src = (const uint4*)(Wt + nr * 128 + s0);
        #pragma unroll
        for (int i = 0; i < 8; i++)
            *(uint4*)&Bs[nr][s0 + i * 8] = src[i];
    }
    __syncthreads();

    const int w = t >> 6, lane = t & 63;
    const int mr = lane & 15, quad = lane >> 4;
    const int m0 = w * 16;

    v4f acc[8];
    #pragma unroll
    for (int nt = 0; nt < 8; nt++) acc[nt] = (v4f){0.f, 0.f, 0.f, 0.f};

    #pragma unroll
    for (int kk = 0; kk < 4; kk++) {
        int kof = kk * 32 + quad * 8;
        v8s a = *(const v8s*)&As[m0 + mr][kof];
        #pragma unroll
        for (int nt = 0; nt < 8; nt++) {
            v8s b = *(const v8s*)&Bs[nt * 16 + mr][kof];
            acc[nt] = __builtin_amdgcn_mfma_f32_16x16x32_bf16(a, b, acc[nt], 0, 0, 0);
        }
    }

    #pragma unroll
    for (int nt = 0; nt < 8; nt++)
        #pragma unroll
        for (int r = 0; r < 4; r++)
            As[m0 + quad * 4 + r][nt * 16 + mr] = f2bf(acc[nt][r]);
    __syncthreads();
    {
        int row = m0 + (lane >> 2);
        int c0  = (lane & 3) * 32;        // 32 cols = one head
        int n = n0 + row;
        if (n < N_NODES) {
            float ds = 0.f, dd = 0.f;
            #pragma unroll
            for (int i = 0; i < 4; i++) {
                uint4 v = *(const uint4*)&As[row][c0 + i * 8];
                *(uint4*)&h16[(size_t)n * F_DIM + c0 + i * 8] = v;
                float f0 = lo2f(v.x), f1 = hi2f(v.x);
                float f2 = lo2f(v.y), f3 = hi2f(v.y);
                float f4 = lo2f(v.z), f5 = hi2f(v.z);
                float f6 = lo2f(v.w), f7 = hi2f(v.w);
                const float* ps = &attl[c0 + i * 8];
                const float* pd = &attl[128 + c0 + i * 8];
                ds += f0*ps[0] + f1*ps[1] + f2*ps[2] + f3*ps[3]
                    + f4*ps[4] + f5*ps[5] + f6*ps[6] + f7*ps[7];
                dd += f0*pd[0] + f1*pd[1] + f2*pd[2] + f3*pd[3]
                    + f4*pd[4] + f5*pd[5] + f6*pd[6] + f7*pd[7];
            }
            int hd = lane & 3;
            a_src[n * 4 + hd] = ds;
            a_dst[n * 4 + hd] = dd;
        }
    }
}

// Pass D: finalize CSR (R3-proven body; static bucket regions).
// Pad slots carry PADBIT so k_agg zeroes their contribution.
__global__ __launch_bounds__(512) void k_csrfin(const int* __restrict__ ebuf,
                                                const int* __restrict__ pcur,
                                                int2* __restrict__ ebounds,
                                                int* __restrict__ csr2) {
    __shared__ int cnt[128];
    __shared__ int off[128];
    __shared__ int wtot;
    int b = blockIdx.x;
    int beg = b * BUCK_CAP;
    int end = beg + pcur[b * CURSTRIDE];
    int padded_base = b * CSR_STRIDE;
    int tid = threadIdx.x;
    if (tid < 128) cnt[tid] = 0;
    __syncthreads();
    {
        int j = beg + tid;
        for (; j + 3 * 512 < end; j += 4 * 512) {
            int e0 = ebuf[j];
            int e1 = ebuf[j + 512];
            int e2 = ebuf[j + 1024];
            int e3 = ebuf[j + 1536];
            atomicAdd(&cnt[(e0 >> 17) & 127], 1);
            atomicAdd(&cnt[(e1 >> 17) & 127], 1);
            atomicAdd(&cnt[(e2 >> 17) & 127], 1);
            atomicAdd(&cnt[(e3 >> 17) & 127], 1);
        }
        for (; j < end; j += 512)
            atomicAdd(&cnt[(ebuf[j] >> 17) & 127], 1);
    }
    __syncthreads();
    // parallel exclusive scan of padded counts (128 entries across 2 waves)
    if (tid < 128) {
        int cp = (cnt[tid] + 3) & ~3;
        int x = cp;
        #pragma unroll
        for (int o = 1; o < 64; o <<= 1) {
            int y = __shfl_up(x, o, 64);
            if ((tid & 63) >= o) x += y;
        }
        off[tid] = x - cp;                 // exclusive within wave
        if (tid == 63) wtot = x;           // wave-0 inclusive total
    }
    __syncthreads();
    if (tid < 128) {
        int v = off[tid] + ((tid >= 64) ? wtot : 0) + padded_base;
        off[tid] = v;
        int node = (b << BUCKW_LOG) + tid;
        int c = cnt[tid];
        if (node < N_NODES) {
            ebounds[node] = make_int2(v, v + c);
            int cpad = (c + 3) & ~3;
            for (int k = c; k < cpad; k++)       // pad slots: self idx + PADBIT
                csr2[v + k] = node | PADBIT;
        }
        cnt[tid] = 0;               // reuse as cursors
    }
    __syncthreads();
    {
        int j = beg + tid;
        for (; j + 3 * 512 < end; j += 4 * 512) {
            int e0 = ebuf[j];
            int e1 = ebuf[j + 512];
            int e2 = ebuf[j + 1024];
            int e3 = ebuf[j + 1536];
            int d0 = (e0 >> 17) & 127; int r0 = atomicAdd(&cnt[d0], 1);
            csr2[off[d0] + r0] = e0 & 0x1ffff;
            int d1 = (e1 >> 17) & 127; int r1 = atomicAdd(&cnt[d1], 1);
            csr2[off[d1] + r1] = e1 & 0x1ffff;
            int d2 = (e2 >> 17) & 127; int r2 = atomicAdd(&cnt[d2], 1);
            csr2[off[d2] + r2] = e2 & 0x1ffff;
            int d3 = (e3 >> 17) & 127; int r3 = atomicAdd(&cnt[d3], 1);
            csr2[off[d3] + r3] = e3 & 0x1ffff;
        }
        for (; j < end; j += 512) {
            int e0 = ebuf[j];
            int d0 = (e0 >> 17) & 127; int r0 = atomicAdd(&cnt[d0], 1);
            csr2[off[d0] + r0] = e0 & 0x1ffff;
        }
    }
}

// ---------------- aggregation: one wave per dst, 4 groups x unroll 2 ---------
// R4-proven: inline weights + 1-deep index prefetch (78.3us measured).
__global__ __launch_bounds__(256) void k_agg(const uint4* __restrict__ h16x4,
                                             const float* __restrict__ a_src,
                                             const float* __restrict__ a_dst,
                                             const int2* __restrict__ ebounds,
                                             const int* __restrict__ csr2,
                                             const float* __restrict__ bias,
                                             float* __restrict__ out) {
    int n = (blockIdx.x * 256 + threadIdx.x) >> 6;
    if (n >= N_NODES) return;
    int lane = threadIdx.x & 63;
    int grp = lane >> 4, g = lane & 15, hd = g >> 2;

    float adn = a_dst[n * 4 + hd];         // wave-constant per head
    float p0 = 0.f;
    if (grp == 0) {
        float e0 = a_src[n * 4 + hd] + adn;
        e0 = e0 > 0.f ? e0 : NEG_SLOPE * e0;
        p0 = __expf(e0);                   // self-loop (group 0 only)
    }
    uint4 hs = h16x4[(size_t)n * 16 + g];
    float l  = p0;
    float a0 = p0 * lo2f(hs.x), a1 = p0 * hi2f(hs.x);
    float a2 = p0 * lo2f(hs.y), a3 = p0 * hi2f(hs.y);
    float a4 = p0 * lo2f(hs.z), a5 = p0 * hi2f(hs.z);
    float a6 = p0 * lo2f(hs.w), a7 = p0 * hi2f(hs.w);

    int2 eb = ebounds[n];
    int beg = eb.x, cnt = eb.y - eb.x;
    const int* sp = csr2 + beg + grp;
    int steps = (cnt + 3) >> 2;
    // prefetched indices for steps t and t+1
    int u0 = (steps > 0) ? sp[0] : 0;
    int u1 = (steps > 1) ? sp[4] : 0;
    int t = 0;
    for (; t + 2 <= steps; t += 2) {
        int s0 = u0 & 0x7fffffff;
        int s1 = u1 & 0x7fffffff;
        int m0 = u0, m1 = u1;              // keep pad flags
        float as0 = a_src[s0 * 4 + hd];
        float as1 = a_src[s1 * 4 + hd];
        uint4 h0 = h16x4[(size_t)s0 * 16 + g];
        uint4 h1 = h16x4[(size_t)s1 * 16 + g];
        int tn = t + 2;                    // prefetch next pair (masked)
        u0 = (tn < steps) ? sp[4 * tn] : 0;
        u1 = (tn + 1 < steps) ? sp[4 * tn + 4] : 0;
        float w0 = as0 + adn; w0 = w0 > 0.f ? w0 : NEG_SLOPE * w0;
        float w1 = as1 + adn; w1 = w1 > 0.f ? w1 : NEG_SLOPE * w1;
        float q0 = __expf(w0);
        float q1 = __expf(w1);
        q0 = m0 < 0 ? 0.f : q0;            // pad slot -> zero weight
        q1 = m1 < 0 ? 0.f : q1;
        l  += q0 + q1;
        a0 += q0 * lo2f(h0.x) + q1 * lo2f(h1.x);
        a1 += q0 * hi2f(h0.x) + q1 * hi2f(h1.x);
        a2 += q0 * lo2f(h0.y) + q1 * lo2f(h1.y);
        a3 += q0 * hi2f(h0.y) + q1 * hi2f(h1.y);
        a4 += q0 * lo2f(h0.z) + q1 * lo2f(h1.z);
        a5 += q0 * hi2f(h0.z) + q1 * hi2f(h1.z);
        a6 += q0 * lo2f(h0.w) + q1 * lo2f(h1.w);
        a7 += q0 * hi2f(h0.w) + q1 * hi2f(h1.w);
    }
    if (t < steps) {
        int s0 = u0 & 0x7fffffff;
        int m0 = u0;
        float as0 = a_src[s0 * 4 + hd];
        uint4 h0 = h16x4[(size_t)s0 * 16 + g];
        float w0 = as0 + adn; w0 = w0 > 0.f ? w0 : NEG_SLOPE * w0;
        float q0 = __expf(w0);
        q0 = m0 < 0 ? 0.f : q0;
        l  += q0;
        a0 += q0 * lo2f(h0.x);
        a1 += q0 * hi2f(h0.x);
        a2 += q0 * lo2f(h0.y);
        a3 += q0 * hi2f(h0.y);
        a4 += q0 * lo2f(h0.z);
        a5 += q0 * hi2f(h0.z);
        a6 += q0 * lo2f(h0.w);
        a7 += q0 * hi2f(h0.w);
    }
    #define RED2(v) v += __shfl_xor(v, 16, 64); v += __shfl_xor(v, 32, 64);
    RED2(l); RED2(a0); RED2(a1); RED2(a2); RED2(a3);
    RED2(a4); RED2(a5); RED2(a6); RED2(a7);
    #undef RED2

    if (grp == 0) {
        float inv = 1.f / (l + 1e-16f);
        float4 b0 = *(const float4*)&bias[g * 8];
        float4 b1 = *(const float4*)&bias[g * 8 + 4];
        float o0 = a0 * inv + b0.x, o1 = a1 * inv + b0.y;
        float o2 = a2 * inv + b0.z, o3 = a3 * inv + b0.w;
        float o4 = a4 * inv + b1.x, o5 = a5 * inv + b1.y;
        float o6 = a6 * inv + b1.z, o7 = a7 * inv + b1.w;
        // branchless ELU via fast exp
        o0 = o0 > 0.f ? o0 : __expf(o0) - 1.f;
        o1 = o1 > 0.f ? o1 : __expf(o1) - 1.f;
        o2 = o2 > 0.f ? o2 : __expf(o2) - 1.f;
        o3 = o3 > 0.f ? o3 : __expf(o3) - 1.f;
        o4 = o4 > 0.f ? o4 : __expf(o4) - 1.f;
        o5 = o5 > 0.f ? o5 : __expf(o5) - 1.f;
        o6 = o6 > 0.f ? o6 : __expf(o6) - 1.f;
        o7 = o7 > 0.f ? o7 : __expf(o7) - 1.f;
        *(float4*)&out[(size_t)n * F_DIM + g * 8]     = make_float4(o0, o1, o2, o3);
        *(float4*)&out[(size_t)n * F_DIM + g * 8 + 4] = make_float4(o4, o5, o6, o7);
    }
}

extern "C" void kernel_launch(void* const* d_in, const int* in_sizes, int n_in,
                              void* d_out, int out_size, void* d_ws, size_t ws_size,
                              hipStream_t stream) {
    const float* x       = (const float*)d_in[0];
    const int*   ei      = (const int*)d_in[1];   // (2, E) row-major int32
    const float* W       = (const float*)d_in[2];
    const float* att_src = (const float*)d_in[3];
    const float* att_dst = (const float*)d_in[4];
    const float* bias    = (const float*)d_in[5];
    float*       out     = (float*)d_out;

    char* ws = (char*)d_ws;
    unsigned short* h16 = (unsigned short*)ws; ws += (size_t)N_NODES * F_DIM * 2;   // 25.6 MB
    unsigned short* Wt  = (unsigned short*)ws; ws += (size_t)IN_DIM * F_DIM * 2;    // 32 KB
    float* a_src  = (float*)ws; ws += (size_t)N_NODES * 4 * 4;                      // 1.6 MB
    float* a_dst  = (float*)ws; ws += (size_t)N_NODES * 4 * 4;                      // 1.6 MB
    int*   pcur   = (int*)ws;   ws += (size_t)NBUCK * CURSTRIDE * 4;                // 50 KB
    int2*  ebounds= (int2*)ws;  ws += (size_t)N_NODES * 8 + 512;                    // 0.8 MB
    int*   ebuf   = (int*)ws;   ws += (size_t)NBUCK * BUCK_CAP * 4;                 // 9.6 MB
    int*   csr2   = (int*)ws;   ws += (size_t)NBUCK * CSR_STRIDE * 4;               // 11.2 MB

    k_init<<<17, 1024, 0, stream>>>(W, Wt, pcur);
    k_mega<<<GB + SBB, 256, 0, stream>>>(x, Wt, h16, att_src, att_dst,
                                         a_src, a_dst, ei, pcur, ebuf);
    k_csrfin<<<NBUCK, 512, 0, stream>>>(ebuf, pcur, ebounds, csr2);
    k_agg<<<(N_NODES * 64 + 255) / 256, 256, 0, stream>>>((const uint4*)h16, a_src, a_dst, ebounds, csr2, bias, out);
}

// Round 7
// 262.131 us; speedup vs baseline: 6.3856x; 1.2847x over previous
//
#include <hip/hip_runtime.h>
#include <hip/hip_fp16.h>
#include <math.h>

#define N_NODES 100000
#define N_EDGES 1600000
#define IN_DIM 128
#define F_DIM 128      // HEADS*OUT_DIM
#define NEG_SLOPE 0.2f

#define BUCKW_LOG 7            // 128 nodes per bucket
#define NBUCK 784              // covers 100352 >= N_NODES
#define NBLK_S 100             // bscat blocks (fused after gemm blocks)
#define EPSB 16000             // edges per bscat block (NBLK_S*EPSB == N_EDGES)
#define SLAB_CAP 60            // ebuf slots per (bucket,block) slab (mean 20.5, +8.8 sigma)
#define CSR_STRIDE 3072        // csr2 slots/bucket (edges ~2048+14sig + 384 pads)
#define GB 1563                // gemm blocks: ceil(100000/64)
#define PADBIT 0x80000000u

typedef short v8s __attribute__((ext_vector_type(8)));
typedef float v4f __attribute__((ext_vector_type(4)));

static __device__ __forceinline__ unsigned short f2bf(float f) {
    unsigned u = __float_as_uint(f);
    u += 0x7fffu + ((u >> 16) & 1u);
    return (unsigned short)(u >> 16);
}
static __device__ __forceinline__ float lo2f(unsigned u) { return __uint_as_float(u << 16); }
static __device__ __forceinline__ float hi2f(unsigned u) { return __uint_as_float(u & 0xffff0000u); }

// ---------------- init: W transpose/convert ----------------------------------
__global__ __launch_bounds__(1024) void k_init(const float* __restrict__ W,
                                               unsigned short* __restrict__ Wt) {
    int i = blockIdx.x * 1024 + threadIdx.x;   // 16384 elems
    int n = i >> 7, k = i & 127;
    Wt[n * 128 + k] = f2bf(W[k * 128 + n]);
}

// ---------------- MEGA: GEMM tiles (blocks < GB) + bscat (blocks >= GB) ------
// GEMM: h16 = bf16(x @ W) via MFMA, fused a_src/a_dst epilogue (proven).
// bscat: block-PRIVATE LDS cursors (R6's global cursors = 2040 serialized
// same-address atomics each, 167us) + static per-(bucket,block) slabs, so no
// scan chain is needed. Cursor array aliases As (no extra LDS).
__global__ __launch_bounds__(256) void k_mega(const float* __restrict__ x,
                                              const unsigned short* __restrict__ Wt,
                                              unsigned short* __restrict__ h16,
                                              const float* __restrict__ att_src,
                                              const float* __restrict__ att_dst,
                                              float* __restrict__ a_src,
                                              float* __restrict__ a_dst,
                                              const int* __restrict__ ei,
                                              int* __restrict__ pcnt,
                                              int* __restrict__ ebuf) {
    __shared__ unsigned short As[64][136];    // [row][k]  (aliased by bscat cursors)
    __shared__ unsigned short Bs[128][136];   // [n][k]
    __shared__ float attl[256];               // [0..127]=att_src, [128..255]=att_dst
    const int t = threadIdx.x;

    if (blockIdx.x >= GB) {               // ---- bscat part ----
        int blk = blockIdx.x - GB;
        int* cur = (int*)&As[0][0];       // 784 ints, block-private
        for (int i = t; i < NBUCK; i += 256) cur[i] = 0;
        __syncthreads();
        const int4* ps = (const int4*)(ei + blk * EPSB);
        const int4* pd = (const int4*)(ei + N_EDGES + blk * EPSB);
        for (int i = t; i < EPSB / 4; i += 256) {
            int4 s = ps[i];
            int4 d = pd[i];
            int b0 = d.x >> BUCKW_LOG; int r0 = atomicAdd(&cur[b0], 1);
            ebuf[(size_t)(b0 * NBLK_S + blk) * SLAB_CAP + r0] = s.x | ((d.x & 127) << 17);
            int b1 = d.y >> BUCKW_LOG; int r1 = atomicAdd(&cur[b1], 1);
            ebuf[(size_t)(b1 * NBLK_S + blk) * SLAB_CAP + r1] = s.y | ((d.y & 127) << 17);
            int b2 = d.z >> BUCKW_LOG; int r2 = atomicAdd(&cur[b2], 1);
            ebuf[(size_t)(b2 * NBLK_S + blk) * SLAB_CAP + r2] = s.z | ((d.z & 127) << 17);
            int b3 = d.w >> BUCKW_LOG; int r3 = atomicAdd(&cur[b3], 1);
            ebuf[(size_t)(b3 * NBLK_S + blk) * SLAB_CAP + r3] = s.w | ((d.w & 127) << 17);
        }
        __syncthreads();
        for (int b = t; b < NBUCK; b += 256) pcnt[b * NBLK_S + blk] = cur[b];
        return;
    }

    const int n0 = blockIdx.x * 64;
    attl[t] = (t < 128) ? att_src[t] : att_dst[t - 128];

    {
        int row = t >> 2, k0 = (t & 3) * 32;
        int n = n0 + row;
        #pragma unroll
        for (int i = 0; i < 4; i++) {
            float4 va = make_float4(0.f,0.f,0.f,0.f), vb = va;
            if (n < N_NODES) {
                const float* p = x + (size_t)n * IN_DIM + k0 + i * 8;
                va = *(const float4*)p;
                vb = *(const float4*)(p + 4);
            }
            uint4 u;
            u.x = f2bf(va.x) | ((unsigned)f2bf(va.y) << 16);
            u.y = f2bf(va.z) | ((unsigned)f2bf(va.w) << 16);
            u.z = f2bf(vb.x) | ((unsigned)f2bf(vb.y) << 16);
            u.w = f2bf(vb.z) | ((unsigned)f2bf(vb.w) << 16);
            *(uint4*)&As[row][k0 + i * 8] = u;
        }
    }
    {
        int nr = t >> 1, s0 = (t & 1) * 64;
        const uint4* src = (const uint4*)(Wt + nr * 128 + s0);
        #pragma unroll
        for (int i = 0; i < 8; i++)
            *(uint4*)&Bs[nr][s0 + i * 8] = src[i];
    }
    __syncthreads();

    const int w = t >> 6, lane = t & 63;
    const int mr = lane & 15, quad = lane >> 4;
    const int m0 = w * 16;

    v4f acc[8];
    #pragma unroll
    for (int nt = 0; nt < 8; nt++) acc[nt] = (v4f){0.f, 0.f, 0.f, 0.f};

    #pragma unroll
    for (int kk = 0; kk < 4; kk++) {
        int kof = kk * 32 + quad * 8;
        v8s a = *(const v8s*)&As[m0 + mr][kof];
        #pragma unroll
        for (int nt = 0; nt < 8; nt++) {
            v8s b = *(const v8s*)&Bs[nt * 16 + mr][kof];
            acc[nt] = __builtin_amdgcn_mfma_f32_16x16x32_bf16(a, b, acc[nt], 0, 0, 0);
        }
    }

    #pragma unroll
    for (int nt = 0; nt < 8; nt++)
        #pragma unroll
        for (int r = 0; r < 4; r++)
            As[m0 + quad * 4 + r][nt * 16 + mr] = f2bf(acc[nt][r]);
    __syncthreads();
    {
        int row = m0 + (lane >> 2);
        int c0  = (lane & 3) * 32;        // 32 cols = one head
        int n = n0 + row;
        if (n < N_NODES) {
            float ds = 0.f, dd = 0.f;
            #pragma unroll
            for (int i = 0; i < 4; i++) {
                uint4 v = *(const uint4*)&As[row][c0 + i * 8];
                *(uint4*)&h16[(size_t)n * F_DIM + c0 + i * 8] = v;
                float f0 = lo2f(v.x), f1 = hi2f(v.x);
                float f2 = lo2f(v.y), f3 = hi2f(v.y);
                float f4 = lo2f(v.z), f5 = hi2f(v.z);
                float f6 = lo2f(v.w), f7 = hi2f(v.w);
                const float* ps = &attl[c0 + i * 8];
                const float* pd = &attl[128 + c0 + i * 8];
                ds += f0*ps[0] + f1*ps[1] + f2*ps[2] + f3*ps[3]
                    + f4*ps[4] + f5*ps[5] + f6*ps[6] + f7*ps[7];
                dd += f0*pd[0] + f1*pd[1] + f2*pd[2] + f3*pd[3]
                    + f4*pd[4] + f5*pd[5] + f6*pd[6] + f7*pd[7];
            }
            int hd = lane & 3;
            a_src[n * 4 + hd] = ds;
            a_dst[n * 4 + hd] = dd;
        }
    }
}

// Pass D: finalize CSR (R3-proven two-phase body; reads 100 static slabs).
// Pad slots carry PADBIT so k_agg zeroes their contribution.
__global__ __launch_bounds__(512) void k_csrfin(const int* __restrict__ ebuf,
                                                const int* __restrict__ pcnt,
                                                int2* __restrict__ ebounds,
                                                int* __restrict__ csr2) {
    __shared__ int cnt[128];
    __shared__ int off[128];
    __shared__ int scnt[NBLK_S];
    __shared__ int wtot;
    int b = blockIdx.x, tid = threadIdx.x;
    if (tid < NBLK_S) scnt[tid] = pcnt[b * NBLK_S + tid];
    if (tid < 128) cnt[tid] = 0;
    __syncthreads();
    int s = tid >> 2, i0 = tid & 3;       // 4 threads per slab
    const int* sb = ebuf + (size_t)(b * NBLK_S + s) * SLAB_CAP;
    int c = (s < NBLK_S) ? scnt[s] : 0;
    {   // phase 1: histogram of local dst (unroll 2 for MLP)
        int i = i0;
        for (; i + 4 < c; i += 8) {
            int e0 = sb[i];
            int e1 = sb[i + 4];
            atomicAdd(&cnt[(e0 >> 17) & 127], 1);
            atomicAdd(&cnt[(e1 >> 17) & 127], 1);
        }
        if (i < c) atomicAdd(&cnt[(sb[i] >> 17) & 127], 1);
    }
    __syncthreads();
    // parallel exclusive scan of padded counts (128 entries across 2 waves)
    if (tid < 128) {
        int cp = (cnt[tid] + 3) & ~3;
        int x = cp;
        #pragma unroll
        for (int o = 1; o < 64; o <<= 1) {
            int y = __shfl_up(x, o, 64);
            if ((tid & 63) >= o) x += y;
        }
        off[tid] = x - cp;                 // exclusive within wave
        if (tid == 63) wtot = x;           // wave-0 inclusive total
    }
    __syncthreads();
    if (tid < 128) {
        int v = off[tid] + ((tid >= 64) ? wtot : 0) + b * CSR_STRIDE;
        off[tid] = v;
        int node = (b << BUCKW_LOG) + tid;
        int cc = cnt[tid];
        if (node < N_NODES) {
            ebounds[node] = make_int2(v, v + cc);
            int cpad = (cc + 3) & ~3;
            for (int k = cc; k < cpad; k++)      // pad slots: self idx + PADBIT
                csr2[v + k] = node | PADBIT;
        }
        cnt[tid] = 0;               // reuse as cursors
    }
    __syncthreads();
    {   // phase 2: place edges (order within node irrelevant — it's a sum)
        int i = i0;
        for (; i + 4 < c; i += 8) {
            int e0 = sb[i];
            int e1 = sb[i + 4];
            int d0 = (e0 >> 17) & 127; int r0 = atomicAdd(&cnt[d0], 1);
            csr2[off[d0] + r0] = e0 & 0x1ffff;
            int d1 = (e1 >> 17) & 127; int r1 = atomicAdd(&cnt[d1], 1);
            csr2[off[d1] + r1] = e1 & 0x1ffff;
        }
        if (i < c) {
            int e0 = sb[i];
            int d0 = (e0 >> 17) & 127; int r0 = atomicAdd(&cnt[d0], 1);
            csr2[off[d0] + r0] = e0 & 0x1ffff;
        }
    }
}

// ---------------- aggregation: one wave per dst, 4 groups x unroll 2 ---------
// R4-proven: inline weights + 1-deep index prefetch (78.3us measured).
__global__ __launch_bounds__(256) void k_agg(const uint4* __restrict__ h16x4,
                                             const float* __restrict__ a_src,
                                             const float* __restrict__ a_dst,
                                             const int2* __restrict__ ebounds,
                                             const int* __restrict__ csr2,
                                             const float* __restrict__ bias,
                                             float* __restrict__ out) {
    int n = (blockIdx.x * 256 + threadIdx.x) >> 6;
    if (n >= N_NODES) return;
    int lane = threadIdx.x & 63;
    int grp = lane >> 4, g = lane & 15, hd = g >> 2;

    float adn = a_dst[n * 4 + hd];         // wave-constant per head
    float p0 = 0.f;
    if (grp == 0) {
        float e0 = a_src[n * 4 + hd] + adn;
        e0 = e0 > 0.f ? e0 : NEG_SLOPE * e0;
        p0 = __expf(e0);                   // self-loop (group 0 only)
    }
    uint4 hs = h16x4[(size_t)n * 16 + g];
    float l  = p0;
    float a0 = p0 * lo2f(hs.x), a1 = p0 * hi2f(hs.x);
    float a2 = p0 * lo2f(hs.y), a3 = p0 * hi2f(hs.y);
    float a4 = p0 * lo2f(hs.z), a5 = p0 * hi2f(hs.z);
    float a6 = p0 * lo2f(hs.w), a7 = p0 * hi2f(hs.w);

    int2 eb = ebounds[n];
    int beg = eb.x, cnt = eb.y - eb.x;
    const int* sp = csr2 + beg + grp;
    int steps = (cnt + 3) >> 2;
    // prefetched indices for steps t and t+1
    int u0 = (steps > 0) ? sp[0] : 0;
    int u1 = (steps > 1) ? sp[4] : 0;
    int t = 0;
    for (; t + 2 <= steps; t += 2) {
        int s0 = u0 & 0x7fffffff;
        int s1 = u1 & 0x7fffffff;
        int m0 = u0, m1 = u1;              // keep pad flags
        float as0 = a_src[s0 * 4 + hd];
        float as1 = a_src[s1 * 4 + hd];
        uint4 h0 = h16x4[(size_t)s0 * 16 + g];
        uint4 h1 = h16x4[(size_t)s1 * 16 + g];
        int tn = t + 2;                    // prefetch next pair (masked)
        u0 = (tn < steps) ? sp[4 * tn] : 0;
        u1 = (tn + 1 < steps) ? sp[4 * tn + 4] : 0;
        float w0 = as0 + adn; w0 = w0 > 0.f ? w0 : NEG_SLOPE * w0;
        float w1 = as1 + adn; w1 = w1 > 0.f ? w1 : NEG_SLOPE * w1;
        float q0 = __expf(w0);
        float q1 = __expf(w1);
        q0 = m0 < 0 ? 0.f : q0;            // pad slot -> zero weight
        q1 = m1 < 0 ? 0.f : q1;
        l  += q0 + q1;
        a0 += q0 * lo2f(h0.x) + q1 * lo2f(h1.x);
        a1 += q0 * hi2f(h0.x) + q1 * hi2f(h1.x);
        a2 += q0 * lo2f(h0.y) + q1 * lo2f(h1.y);
        a3 += q0 * hi2f(h0.y) + q1 * hi2f(h1.y);
        a4 += q0 * lo2f(h0.z) + q1 * lo2f(h1.z);
        a5 += q0 * hi2f(h0.z) + q1 * hi2f(h1.z);
        a6 += q0 * lo2f(h0.w) + q1 * lo2f(h1.w);
        a7 += q0 * hi2f(h0.w) + q1 * hi2f(h1.w);
    }
    if (t < steps) {
        int s0 = u0 & 0x7fffffff;
        int m0 = u0;
        float as0 = a_src[s0 * 4 + hd];
        uint4 h0 = h16x4[(size_t)s0 * 16 + g];
        float w0 = as0 + adn; w0 = w0 > 0.f ? w0 : NEG_SLOPE * w0;
        float q0 = __expf(w0);
        q0 = m0 < 0 ? 0.f : q0;
        l  += q0;
        a0 += q0 * lo2f(h0.x);
        a1 += q0 * hi2f(h0.x);
        a2 += q0 * lo2f(h0.y);
        a3 += q0 * hi2f(h0.y);
        a4 += q0 * lo2f(h0.z);
        a5 += q0 * hi2f(h0.z);
        a6 += q0 * lo2f(h0.w);
        a7 += q0 * hi2f(h0.w);
    }
    #define RED2(v) v += __shfl_xor(v, 16, 64); v += __shfl_xor(v, 32, 64);
    RED2(l); RED2(a0); RED2(a1); RED2(a2); RED2(a3);
    RED2(a4); RED2(a5); RED2(a6); RED2(a7);
    #undef RED2

    if (grp == 0) {
        float inv = 1.f / (l + 1e-16f);
        float4 b0 = *(const float4*)&bias[g * 8];
        float4 b1 = *(const float4*)&bias[g * 8 + 4];
        float o0 = a0 * inv + b0.x, o1 = a1 * inv + b0.y;
        float o2 = a2 * inv + b0.z, o3 = a3 * inv + b0.w;
        float o4 = a4 * inv + b1.x, o5 = a5 * inv + b1.y;
        float o6 = a6 * inv + b1.z, o7 = a7 * inv + b1.w;
        // branchless ELU via fast exp
        o0 = o0 > 0.f ? o0 : __expf(o0) - 1.f;
        o1 = o1 > 0.f ? o1 : __expf(o1) - 1.f;
        o2 = o2 > 0.f ? o2 : __expf(o2) - 1.f;
        o3 = o3 > 0.f ? o3 : __expf(o3) - 1.f;
        o4 = o4 > 0.f ? o4 : __expf(o4) - 1.f;
        o5 = o5 > 0.f ? o5 : __expf(o5) - 1.f;
        o6 = o6 > 0.f ? o6 : __expf(o6) - 1.f;
        o7 = o7 > 0.f ? o7 : __expf(o7) - 1.f;
        *(float4*)&out[(size_t)n * F_DIM + g * 8]     = make_float4(o0, o1, o2, o3);
        *(float4*)&out[(size_t)n * F_DIM + g * 8 + 4] = make_float4(o4, o5, o6, o7);
    }
}

extern "C" void kernel_launch(void* const* d_in, const int* in_sizes, int n_in,
                              void* d_out, int out_size, void* d_ws, size_t ws_size,
                              hipStream_t stream) {
    const float* x       = (const float*)d_in[0];
    const int*   ei      = (const int*)d_in[1];   // (2, E) row-major int32
    const float* W       = (const float*)d_in[2];
    const float* att_src = (const float*)d_in[3];
    const float* att_dst = (const float*)d_in[4];
    const float* bias    = (const float*)d_in[5];
    float*       out     = (float*)d_out;

    char* ws = (char*)d_ws;
    unsigned short* h16 = (unsigned short*)ws; ws += (size_t)N_NODES * F_DIM * 2;   // 25.6 MB
    unsigned short* Wt  = (unsigned short*)ws; ws += (size_t)IN_DIM * F_DIM * 2;    // 32 KB
    float* a_src  = (float*)ws; ws += (size_t)N_NODES * 4 * 4;                      // 1.6 MB
    float* a_dst  = (float*)ws; ws += (size_t)N_NODES * 4 * 4;                      // 1.6 MB
    int*   pcnt   = (int*)ws;   ws += (size_t)NBUCK * NBLK_S * 4;                   // 0.31 MB
    int2*  ebounds= (int2*)ws;  ws += (size_t)N_NODES * 8 + 512;                    // 0.8 MB
    int*   ebuf   = (int*)ws;   ws += (size_t)NBUCK * NBLK_S * SLAB_CAP * 4;        // 18.8 MB
    int*   csr2   = (int*)ws;   ws += (size_t)NBUCK * CSR_STRIDE * 4;               // 9.6 MB

    k_init<<<16, 1024, 0, stream>>>(W, Wt);
    k_mega<<<GB + NBLK_S, 256, 0, stream>>>(x, Wt, h16, att_src, att_dst,
                                            a_src, a_dst, ei, pcnt, ebuf);
    k_csrfin<<<NBUCK, 512, 0, stream>>>(ebuf, pcnt, ebounds, csr2);
    k_agg<<<(N_NODES * 64 + 255) / 256, 256, 0, stream>>>((const uint4*)h16, a_src, a_dst, ebounds, csr2, bias, out);
}

// Round 8
// 242.243 us; speedup vs baseline: 6.9099x; 1.0821x over previous
//
#include <hip/hip_runtime.h>
#include <hip/hip_fp16.h>
#include <math.h>

#define N_NODES 100000
#define N_EDGES 1600000
#define IN_DIM 128
#define F_DIM 128      // HEADS*OUT_DIM
#define NEG_SLOPE 0.2f

#define BUCKW_LOG 7            // 128 nodes per bucket
#define NBUCK 784              // covers 100352 >= N_NODES
#define NBLK_S 100             // bscat blocks (run FIRST in the mega grid)
#define EPSB 16000             // edges per bscat block (NBLK_S*EPSB == N_EDGES)
#define SLAB_CAP 64            // ebuf slots per (bucket,block) slab (mean 20.4, +9.7 sigma)
#define DEG_CAP 64             // per-node LDS list capacity (mean 16, +12 sigma)
#define GB 1563                // gemm blocks: ceil(100000/64)
#define PADBIT 0x80000000u

typedef short v8s __attribute__((ext_vector_type(8)));
typedef float v4f __attribute__((ext_vector_type(4)));

static __device__ __forceinline__ unsigned short f2bf(float f) {
    unsigned u = __float_as_uint(f);
    u += 0x7fffu + ((u >> 16) & 1u);
    return (unsigned short)(u >> 16);
}
static __device__ __forceinline__ float lo2f(unsigned u) { return __uint_as_float(u << 16); }
static __device__ __forceinline__ float hi2f(unsigned u) { return __uint_as_float(u & 0xffff0000u); }

// ---------------- init: W transpose/convert ----------------------------------
__global__ __launch_bounds__(1024) void k_init(const float* __restrict__ W,
                                               unsigned short* __restrict__ Wt) {
    int i = blockIdx.x * 1024 + threadIdx.x;   // 16384 elems
    int n = i >> 7, k = i & 127;
    Wt[n * 128 + k] = f2bf(W[k * 128 + n]);
}

// ---------------- MEGA: bscat (blocks < NBLK_S, FIRST) + GEMM tiles ----------
// bscat first so its ~28us latency-bound scatter overlaps the gemm instead of
// trailing it (R7: appended bscat blocks ran serially after 1563 gemm blocks).
// Block-private LDS cursors (aliasing As) + static per-(bucket,block) slabs.
__global__ __launch_bounds__(256) void k_mega(const float* __restrict__ x,
                                              const unsigned short* __restrict__ Wt,
                                              unsigned short* __restrict__ h16,
                                              const float* __restrict__ att_src,
                                              const float* __restrict__ att_dst,
                                              float* __restrict__ a_src,
                                              float* __restrict__ a_dst,
                                              const int* __restrict__ ei,
                                              int* __restrict__ pcnt,
                                              int* __restrict__ ebuf) {
    __shared__ unsigned short As[64][136];    // [row][k]  (aliased by bscat cursors)
    __shared__ unsigned short Bs[128][136];   // [n][k]
    __shared__ float attl[256];               // [0..127]=att_src, [128..255]=att_dst
    const int t = threadIdx.x;

    if (blockIdx.x < NBLK_S) {            // ---- bscat part (runs first) ----
        int blk = blockIdx.x;
        int* cur = (int*)&As[0][0];       // 784 ints, block-private
        for (int i = t; i < NBUCK; i += 256) cur[i] = 0;
        __syncthreads();
        const int4* ps = (const int4*)(ei + blk * EPSB);
        const int4* pd = (const int4*)(ei + N_EDGES + blk * EPSB);
        for (int i = t; i < EPSB / 4; i += 256) {
            int4 s = ps[i];
            int4 d = pd[i];
            int b0 = d.x >> BUCKW_LOG; int r0 = atomicAdd(&cur[b0], 1);
            ebuf[((b0 * NBLK_S + blk) << 6) + r0] = s.x | ((d.x & 127) << 17);
            int b1 = d.y >> BUCKW_LOG; int r1 = atomicAdd(&cur[b1], 1);
            ebuf[((b1 * NBLK_S + blk) << 6) + r1] = s.y | ((d.y & 127) << 17);
            int b2 = d.z >> BUCKW_LOG; int r2 = atomicAdd(&cur[b2], 1);
            ebuf[((b2 * NBLK_S + blk) << 6) + r2] = s.z | ((d.z & 127) << 17);
            int b3 = d.w >> BUCKW_LOG; int r3 = atomicAdd(&cur[b3], 1);
            ebuf[((b3 * NBLK_S + blk) << 6) + r3] = s.w | ((d.w & 127) << 17);
        }
        __syncthreads();
        for (int b = t; b < NBUCK; b += 256) pcnt[b * NBLK_S + blk] = cur[b];
        return;
    }

    const int n0 = (blockIdx.x - NBLK_S) * 64;
    attl[t] = (t < 128) ? att_src[t] : att_dst[t - 128];

    {
        int row = t >> 2, k0 = (t & 3) * 32;
        int n = n0 + row;
        #pragma unroll
        for (int i = 0; i < 4; i++) {
            float4 va = make_float4(0.f,0.f,0.f,0.f), vb = va;
            if (n < N_NODES) {
                const float* p = x + (size_t)n * IN_DIM + k0 + i * 8;
                va = *(const float4*)p;
                vb = *(const float4*)(p + 4);
            }
            uint4 u;
            u.x = f2bf(va.x) | ((unsigned)f2bf(va.y) << 16);
            u.y = f2bf(va.z) | ((unsigned)f2bf(va.w) << 16);
            u.z = f2bf(vb.x) | ((unsigned)f2bf(vb.y) << 16);
            u.w = f2bf(vb.z) | ((unsigned)f2bf(vb.w) << 16);
            *(uint4*)&As[row][k0 + i * 8] = u;
        }
    }
    {
        int nr = t >> 1, s0 = (t & 1) * 64;
        const uint4* src = (const uint4*)(Wt + nr * 128 + s0);
        #pragma unroll
        for (int i = 0; i < 8; i++)
            *(uint4*)&Bs[nr][s0 + i * 8] = src[i];
    }
    __syncthreads();

    const int w = t >> 6, lane = t & 63;
    const int mr = lane & 15, quad = lane >> 4;
    const int m0 = w * 16;

    v4f acc[8];
    #pragma unroll
    for (int nt = 0; nt < 8; nt++) acc[nt] = (v4f){0.f, 0.f, 0.f, 0.f};

    #pragma unroll
    for (int kk = 0; kk < 4; kk++) {
        int kof = kk * 32 + quad * 8;
        v8s a = *(const v8s*)&As[m0 + mr][kof];
        #pragma unroll
        for (int nt = 0; nt < 8; nt++) {
            v8s b = *(const v8s*)&Bs[nt * 16 + mr][kof];
            acc[nt] = __builtin_amdgcn_mfma_f32_16x16x32_bf16(a, b, acc[nt], 0, 0, 0);
        }
    }

    #pragma unroll
    for (int nt = 0; nt < 8; nt++)
        #pragma unroll
        for (int r = 0; r < 4; r++)
            As[m0 + quad * 4 + r][nt * 16 + mr] = f2bf(acc[nt][r]);
    __syncthreads();
    {
        int row = m0 + (lane >> 2);
        int c0  = (lane & 3) * 32;        // 32 cols = one head
        int n = n0 + row;
        if (n < N_NODES) {
            float ds = 0.f, dd = 0.f;
            #pragma unroll
            for (int i = 0; i < 4; i++) {
                uint4 v = *(const uint4*)&As[row][c0 + i * 8];
                *(uint4*)&h16[(size_t)n * F_DIM + c0 + i * 8] = v;
                float f0 = lo2f(v.x), f1 = hi2f(v.x);
                float f2 = lo2f(v.y), f3 = hi2f(v.y);
                float f4 = lo2f(v.z), f5 = hi2f(v.z);
                float f6 = lo2f(v.w), f7 = hi2f(v.w);
                const float* ps = &attl[c0 + i * 8];
                const float* pd = &attl[128 + c0 + i * 8];
                ds += f0*ps[0] + f1*ps[1] + f2*ps[2] + f3*ps[3]
                    + f4*ps[4] + f5*ps[5] + f6*ps[6] + f7*ps[7];
                dd += f0*pd[0] + f1*pd[1] + f2*pd[2] + f3*pd[3]
                    + f4*pd[4] + f5*pd[5] + f6*pd[6] + f7*pd[7];
            }
            int hd = lane & 3;
            a_src[n * 4 + hd] = ds;
            a_dst[n * 4 + hd] = dd;
        }
    }
}

// ---------------- agg2: one block per bucket ---------------------------------
// Phase 1: coalesced read of the bucket's contiguous 25.6KB slab window ->
// per-node LDS lists via LDS cursors (deletes csrfin + csr2 entirely).
// Phase 2: 16 waves x 8 nodes, R4-proven gather loop with LDS indices.
__global__ __launch_bounds__(1024) void k_agg2(const uint4* __restrict__ h16x4,
                                               const float* __restrict__ a_src,
                                               const float* __restrict__ a_dst,
                                               const int* __restrict__ pcnt,
                                               const int* __restrict__ ebuf,
                                               const float* __restrict__ bias,
                                               float* __restrict__ out) {
    __shared__ int list[128 << 6];     // 128 nodes x 64 slots = 32KB
    __shared__ int cnt[128];
    __shared__ int scnt[NBLK_S];
    const int b = blockIdx.x, t = threadIdx.x;

    if (t < NBLK_S) scnt[t] = pcnt[b * NBLK_S + t];
    if (t < 128) cnt[t] = 0;
    __syncthreads();
    {   // build: 1600 int4 over 1024 threads
        const int4* win = (const int4*)(ebuf + (size_t)b * (NBLK_S * SLAB_CAP));
        #pragma unroll
        for (int it = 0; it < 2; it++) {
            int i4 = it * 1024 + t;
            if (i4 < NBLK_S * SLAB_CAP / 4) {
                int4 e4 = win[i4];
                int base = i4 << 2;
                int es0 = e4.x, es1 = e4.y, es2 = e4.z, es3 = e4.w;
                #define PUT(J, E) {                                            \
                    int idx = base + (J);                                      \
                    if ((idx & 63) < scnt[idx >> 6]) {                         \
                        int dl = ((E) >> 17) & 127;                            \
                        int r = atomicAdd(&cnt[dl], 1);                        \
                        list[(dl << 6) + r] = (E) & 0x1ffff;                   \
                    }                                                          \
                }
                PUT(0, es0); PUT(1, es1); PUT(2, es2); PUT(3, es3);
                #undef PUT
            }
        }
    }
    __syncthreads();
    if (t < 128) {                     // pad each list to multiple of 4
        int c = cnt[t], cp = (c + 3) & ~3;
        for (int k = c; k < cp; k++) list[(t << 6) + k] = (int)PADBIT;
    }
    __syncthreads();

    const int wv = t >> 6, lane = t & 63;
    const int grp = lane >> 4, g = lane & 15, hd = g >> 2;
    const float4 bb0 = *(const float4*)&bias[g * 8];
    const float4 bb1 = *(const float4*)&bias[g * 8 + 4];

    for (int k8 = 0; k8 < 8; k8++) {
        int nl = (wv << 3) + k8;       // wave wv owns nodes [8wv, 8wv+8)
        int n = (b << BUCKW_LOG) + nl;
        if (n >= N_NODES) break;

        float adn = a_dst[n * 4 + hd];
        float p0 = 0.f;
        if (grp == 0) {
            float e0 = a_src[n * 4 + hd] + adn;
            e0 = e0 > 0.f ? e0 : NEG_SLOPE * e0;
            p0 = __expf(e0);           // self-loop (group 0 only)
        }
        uint4 hs = h16x4[(size_t)n * 16 + g];
        float l  = p0;
        float a0 = p0 * lo2f(hs.x), a1 = p0 * hi2f(hs.x);
        float a2 = p0 * lo2f(hs.y), a3 = p0 * hi2f(hs.y);
        float a4 = p0 * lo2f(hs.z), a5 = p0 * hi2f(hs.z);
        float a6 = p0 * lo2f(hs.w), a7 = p0 * hi2f(hs.w);

        int cn = cnt[nl];
        const int* sp = &list[(nl << 6) + grp];
        int steps = (cn + 3) >> 2;
        int tt = 0;
        for (; tt + 2 <= steps; tt += 2) {
            int u0 = sp[4 * tt];
            int u1 = sp[4 * tt + 4];
            int s0 = u0 & 0x7fffffff;
            int s1 = u1 & 0x7fffffff;
            float as0 = a_src[s0 * 4 + hd];
            float as1 = a_src[s1 * 4 + hd];
            uint4 h0 = h16x4[(size_t)s0 * 16 + g];
            uint4 h1 = h16x4[(size_t)s1 * 16 + g];
            float w0 = as0 + adn; w0 = w0 > 0.f ? w0 : NEG_SLOPE * w0;
            float w1 = as1 + adn; w1 = w1 > 0.f ? w1 : NEG_SLOPE * w1;
            float q0 = __expf(w0);
            float q1 = __expf(w1);
            q0 = u0 < 0 ? 0.f : q0;    // pad slot -> zero weight
            q1 = u1 < 0 ? 0.f : q1;
            l  += q0 + q1;
            a0 += q0 * lo2f(h0.x) + q1 * lo2f(h1.x);
            a1 += q0 * hi2f(h0.x) + q1 * hi2f(h1.x);
            a2 += q0 * lo2f(h0.y) + q1 * lo2f(h1.y);
            a3 += q0 * hi2f(h0.y) + q1 * hi2f(h1.y);
            a4 += q0 * lo2f(h0.z) + q1 * lo2f(h1.z);
            a5 += q0 * hi2f(h0.z) + q1 * hi2f(h1.z);
            a6 += q0 * lo2f(h0.w) + q1 * lo2f(h1.w);
            a7 += q0 * hi2f(h0.w) + q1 * hi2f(h1.w);
        }
        if (tt < steps) {
            int u0 = sp[4 * tt];
            int s0 = u0 & 0x7fffffff;
            float as0 = a_src[s0 * 4 + hd];
            uint4 h0 = h16x4[(size_t)s0 * 16 + g];
            float w0 = as0 + adn; w0 = w0 > 0.f ? w0 : NEG_SLOPE * w0;
            float q0 = __expf(w0);
            q0 = u0 < 0 ? 0.f : q0;
            l  += q0;
            a0 += q0 * lo2f(h0.x);
            a1 += q0 * hi2f(h0.x);
            a2 += q0 * lo2f(h0.y);
            a3 += q0 * hi2f(h0.y);
            a4 += q0 * lo2f(h0.z);
            a5 += q0 * hi2f(h0.z);
            a6 += q0 * lo2f(h0.w);
            a7 += q0 * hi2f(h0.w);
        }
        #define RED2(v) v += __shfl_xor(v, 16, 64); v += __shfl_xor(v, 32, 64);
        RED2(l); RED2(a0); RED2(a1); RED2(a2); RED2(a3);
        RED2(a4); RED2(a5); RED2(a6); RED2(a7);
        #undef RED2

        if (grp == 0) {
            float inv = 1.f / (l + 1e-16f);
            float o0 = a0 * inv + bb0.x, o1 = a1 * inv + bb0.y;
            float o2 = a2 * inv + bb0.z, o3 = a3 * inv + bb0.w;
            float o4 = a4 * inv + bb1.x, o5 = a5 * inv + bb1.y;
            float o6 = a6 * inv + bb1.z, o7 = a7 * inv + bb1.w;
            o0 = o0 > 0.f ? o0 : __expf(o0) - 1.f;
            o1 = o1 > 0.f ? o1 : __expf(o1) - 1.f;
            o2 = o2 > 0.f ? o2 : __expf(o2) - 1.f;
            o3 = o3 > 0.f ? o3 : __expf(o3) - 1.f;
            o4 = o4 > 0.f ? o4 : __expf(o4) - 1.f;
            o5 = o5 > 0.f ? o5 : __expf(o5) - 1.f;
            o6 = o6 > 0.f ? o6 : __expf(o6) - 1.f;
            o7 = o7 > 0.f ? o7 : __expf(o7) - 1.f;
            *(float4*)&out[(size_t)n * F_DIM + g * 8]     = make_float4(o0, o1, o2, o3);
            *(float4*)&out[(size_t)n * F_DIM + g * 8 + 4] = make_float4(o4, o5, o6, o7);
        }
    }
}

extern "C" void kernel_launch(void* const* d_in, const int* in_sizes, int n_in,
                              void* d_out, int out_size, void* d_ws, size_t ws_size,
                              hipStream_t stream) {
    const float* x       = (const float*)d_in[0];
    const int*   ei      = (const int*)d_in[1];   // (2, E) row-major int32
    const float* W       = (const float*)d_in[2];
    const float* att_src = (const float*)d_in[3];
    const float* att_dst = (const float*)d_in[4];
    const float* bias    = (const float*)d_in[5];
    float*       out     = (float*)d_out;

    char* ws = (char*)d_ws;
    unsigned short* h16 = (unsigned short*)ws; ws += (size_t)N_NODES * F_DIM * 2;   // 25.6 MB
    unsigned short* Wt  = (unsigned short*)ws; ws += (size_t)IN_DIM * F_DIM * 2;    // 32 KB
    float* a_src  = (float*)ws; ws += (size_t)N_NODES * 4 * 4;                      // 1.6 MB
    float* a_dst  = (float*)ws; ws += (size_t)N_NODES * 4 * 4;                      // 1.6 MB
    int*   pcnt   = (int*)ws;   ws += (size_t)NBUCK * NBLK_S * 4;                   // 0.31 MB
    int*   ebuf   = (int*)ws;   ws += (size_t)NBUCK * NBLK_S * SLAB_CAP * 4;        // 20.1 MB

    k_init<<<16, 1024, 0, stream>>>(W, Wt);
    k_mega<<<GB + NBLK_S, 256, 0, stream>>>(x, Wt, h16, att_src, att_dst,
                                            a_src, a_dst, ei, pcnt, ebuf);
    k_agg2<<<NBUCK, 1024, 0, stream>>>((const uint4*)h16, a_src, a_dst,
                                       pcnt, ebuf, bias, out);
}